// Round 1
// baseline (1413.419 us; speedup 1.0000x reference)
//
#include <hip/hip_runtime.h>
#include <math.h>

#define NN 20000
#define NE 320000
#define ET 32          // edges per tile
#define ST 132         // LDS row stride in floats (128 + 4 pad: breaks bank aliasing across edges)

__device__ __forceinline__ float frelu(float x){ return fmaxf(x, 0.f); }

// ---------------- degree histogram over send ----------------
__global__ void k_deg(const int* __restrict__ eidx, int* __restrict__ deg){
  int t = blockIdx.x*256 + threadIdx.x;
  if(t < NE) atomicAdd(&deg[eidx[t]], 1);
}

// ---------------- per-node precompute: A = s@W1[0:128], B = s@W1[128:256] ----------------
__global__ __launch_bounds__(256) void k_ab(const float* __restrict__ s,
                                            const float* __restrict__ W1,
                                            float* __restrict__ A,
                                            float* __restrict__ B){
  __shared__ float sx[8*128];
  const int nb = blockIdx.x*8;
  for(int i=threadIdx.x; i<8*128; i+=256) sx[i] = s[(size_t)nb*128 + i];
  __syncthreads();
  const int col = threadIdx.x;        // 0..255 : [A cols | B cols]
  const int j = col & 127;
  const float* w = W1 + (col < 128 ? 0 : 128*128) + j;
  float acc[8];
  #pragma unroll
  for(int n=0;n<8;n++) acc[n]=0.f;
  for(int k=0;k<128;k++){
    float wv = w[(size_t)k*128];
    #pragma unroll
    for(int n=0;n<8;n++) acc[n] += sx[n*128+k]*wv;
  }
  float* dst = (col<128 ? A : B) + (size_t)nb*128 + j;
  #pragma unroll
  for(int n=0;n<8;n++) dst[(size_t)n*128] = acc[n];
}

// ---------------- fused edge kernel ----------------
__global__ __launch_bounds__(256) void k_edge(
    const float* __restrict__ v, const int* __restrict__ eidx,
    const float* __restrict__ Wvw, const float* __restrict__ Wvb,
    const float* __restrict__ W1c, const float* __restrict__ b1,
    const float* __restrict__ W2,  const float* __restrict__ b2,
    const float* __restrict__ pW1, const float* __restrict__ pb1,
    const float* __restrict__ pW2, const float* __restrict__ pb2,
    const float* __restrict__ A,   const float* __restrict__ Bn,
    float* __restrict__ Magg, float* __restrict__ Pagg)
{
  __shared__ float B0[ET*ST];   // d  -> later m
  __shared__ float Bv[ET*ST];   // v_ij
  __shared__ float B2[ET*ST];   // h  -> later q
  __shared__ float sEA[ET*16];
  __shared__ float sPM[ET*16];
  __shared__ float sWv[1024];
  __shared__ float sWvb[16];
  __shared__ int sS[ET], sR[ET];
  const int t  = threadIdx.x;
  const int e0 = blockIdx.x * ET;

  for(int i=t;i<1024;i+=256) sWv[i]=Wvw[i];
  if(t<16) sWvb[t]=Wvb[t];
  if(t<ET){ sS[t]=eidx[e0+t]; sR[t]=eidx[NE+e0+t]; }
  __syncthreads();

  // Ph1: d = v[rec] - v[send]   (8 threads/edge, float4)
  {
    const int e = t>>3, q = t&7;
    const float4* vs = (const float4*)(v + (size_t)sS[e]*128);
    const float4* vr = (const float4*)(v + (size_t)sR[e]*128);
    #pragma unroll
    for(int i=0;i<4;i++){
      int f = q + i*8;
      float4 a = vr[f], b = vs[f];
      *(float4*)(B0 + e*ST + f*4) = make_float4(a.x-b.x, a.y-b.y, a.z-b.z, a.w-b.w);
    }
  }
  __syncthreads();

  // Ph2: v_ij = mv_linear(d, Wv) ; edge_attr = sum_b v_ij^2
  {
    const int e = t>>3, q = t&7;   // thread handles out channels o=q and o=q+8
    float a0[8], a1[8];
    #pragma unroll
    for(int b=0;b<8;b++){a0[b]=0.f;a1[b]=0.f;}
    a0[0]=sWvb[q]; a1[0]=sWvb[q+8];
    const float* dp = B0 + e*ST;
    #pragma unroll
    for(int c=0;c<16;c++){
      float4 da=*(const float4*)(dp + c*8);
      float4 db=*(const float4*)(dp + c*8 + 4);
      float4 g0=*(const float4*)(sWv + (q*16+c)*4);
      float4 g1=*(const float4*)(sWv + ((q+8)*16+c)*4);
      // grade map per blade: [0,1,1,1,2,2,2,3]
      a0[0]+=da.x*g0.x; a0[1]+=da.y*g0.y; a0[2]+=da.z*g0.y; a0[3]+=da.w*g0.y;
      a0[4]+=db.x*g0.z; a0[5]+=db.y*g0.z; a0[6]+=db.z*g0.z; a0[7]+=db.w*g0.w;
      a1[0]+=da.x*g1.x; a1[1]+=da.y*g1.y; a1[2]+=da.z*g1.y; a1[3]+=da.w*g1.y;
      a1[4]+=db.x*g1.z; a1[5]+=db.y*g1.z; a1[6]+=db.z*g1.z; a1[7]+=db.w*g1.w;
    }
    *(float4*)(Bv + e*ST + q*8)       = make_float4(a0[0],a0[1],a0[2],a0[3]);
    *(float4*)(Bv + e*ST + q*8 + 4)   = make_float4(a0[4],a0[5],a0[6],a0[7]);
    *(float4*)(Bv + e*ST + (q+8)*8)   = make_float4(a1[0],a1[1],a1[2],a1[3]);
    *(float4*)(Bv + e*ST + (q+8)*8+4) = make_float4(a1[4],a1[5],a1[6],a1[7]);
    float e0s=0.f, e1s=0.f;
    #pragma unroll
    for(int b=0;b<8;b++){ e0s+=a0[b]*a0[b]; e1s+=a1[b]*a1[b]; }
    sEA[e*16+q]=e0s; sEA[e*16+q+8]=e1s;
  }
  __syncthreads();

  // Ph3: h = relu(A[send] + B[rec] + ea@W1c + b1)
  {
    const int j = t&127, eg = t>>7;    // eg 0..1, 16 edges each
    float w1c[16];
    #pragma unroll
    for(int c=0;c<16;c++) w1c[c]=W1c[(size_t)c*128 + j];
    const float bb = b1[j];
    for(int ei=0; ei<16; ei++){
      const int e = eg*16 + ei;
      float acc = A[(size_t)sS[e]*128 + j] + Bn[(size_t)sR[e]*128 + j] + bb;
      #pragma unroll
      for(int c=0;c<16;c++) acc += sEA[e*16+c]*w1c[c];
      B2[e*ST + j] = frelu(acc);
    }
  }
  __syncthreads();

  // Ph4: m = h@W2 + b2 -> B0 ; atomic scatter into Magg[rec]
  {
    const int jq = t&31, eg = t>>5;    // eg 0..7, 4 edges each; 4 cols each
    const int j0 = jq*4;
    float4 bb = *(const float4*)(b2 + j0);
    float acc[4][4];
    #pragma unroll
    for(int a=0;a<4;a++){ acc[a][0]=bb.x; acc[a][1]=bb.y; acc[a][2]=bb.z; acc[a][3]=bb.w; }
    for(int k=0;k<128;k+=4){
      float4 w0=*(const float4*)(W2 + (size_t)(k+0)*128 + j0);
      float4 w1=*(const float4*)(W2 + (size_t)(k+1)*128 + j0);
      float4 w2=*(const float4*)(W2 + (size_t)(k+2)*128 + j0);
      float4 w3=*(const float4*)(W2 + (size_t)(k+3)*128 + j0);
      #pragma unroll
      for(int a=0;a<4;a++){
        float4 h4=*(const float4*)(B2 + (eg*4+a)*ST + k);
        acc[a][0] += h4.x*w0.x + h4.y*w1.x + h4.z*w2.x + h4.w*w3.x;
        acc[a][1] += h4.x*w0.y + h4.y*w1.y + h4.z*w2.y + h4.w*w3.y;
        acc[a][2] += h4.x*w0.z + h4.y*w1.z + h4.z*w2.z + h4.w*w3.z;
        acc[a][3] += h4.x*w0.w + h4.y*w1.w + h4.z*w2.w + h4.w*w3.w;
      }
    }
    #pragma unroll
    for(int a=0;a<4;a++){
      const int e = eg*4+a;
      *(float4*)(B0 + e*ST + j0) = make_float4(acc[a][0],acc[a][1],acc[a][2],acc[a][3]);
      float* mg = Magg + (size_t)sR[e]*128 + j0;
      atomicAdd(mg+0, acc[a][0]); atomicAdd(mg+1, acc[a][1]);
      atomicAdd(mg+2, acc[a][2]); atomicAdd(mg+3, acc[a][3]);
    }
  }
  __syncthreads();

  // Ph5: q = relu(m@pW1 + pb1) -> B2
  {
    const int jq = t&31, eg = t>>5;
    const int j0 = jq*4;
    float4 bb = *(const float4*)(pb1 + j0);
    float acc[4][4];
    #pragma unroll
    for(int a=0;a<4;a++){ acc[a][0]=bb.x; acc[a][1]=bb.y; acc[a][2]=bb.z; acc[a][3]=bb.w; }
    for(int k=0;k<128;k+=4){
      float4 w0=*(const float4*)(pW1 + (size_t)(k+0)*128 + j0);
      float4 w1=*(const float4*)(pW1 + (size_t)(k+1)*128 + j0);
      float4 w2=*(const float4*)(pW1 + (size_t)(k+2)*128 + j0);
      float4 w3=*(const float4*)(pW1 + (size_t)(k+3)*128 + j0);
      #pragma unroll
      for(int a=0;a<4;a++){
        float4 m4=*(const float4*)(B0 + (eg*4+a)*ST + k);
        acc[a][0] += m4.x*w0.x + m4.y*w1.x + m4.z*w2.x + m4.w*w3.x;
        acc[a][1] += m4.x*w0.y + m4.y*w1.y + m4.z*w2.y + m4.w*w3.y;
        acc[a][2] += m4.x*w0.z + m4.y*w1.z + m4.z*w2.z + m4.w*w3.z;
        acc[a][3] += m4.x*w0.w + m4.y*w1.w + m4.z*w2.w + m4.w*w3.w;
      }
    }
    #pragma unroll
    for(int a=0;a<4;a++){
      const int e = eg*4+a;
      *(float4*)(B2 + e*ST + j0) = make_float4(frelu(acc[a][0]),frelu(acc[a][1]),frelu(acc[a][2]),frelu(acc[a][3]));
    }
  }
  __syncthreads();

  // Ph6: pm = q@pW2 + pb2
  {
    const int e = t>>3, jq = t&7;
    float acc0 = pb2[jq], acc1 = pb2[jq+8];
    const float* qp = B2 + e*ST;
    for(int k=0;k<128;k+=4){
      float4 q4 = *(const float4*)(qp + k);
      acc0 += q4.x*pW2[(k+0)*16+jq]   + q4.y*pW2[(k+1)*16+jq]   + q4.z*pW2[(k+2)*16+jq]   + q4.w*pW2[(k+3)*16+jq];
      acc1 += q4.x*pW2[(k+0)*16+jq+8] + q4.y*pW2[(k+1)*16+jq+8] + q4.z*pW2[(k+2)*16+jq+8] + q4.w*pW2[(k+3)*16+jq+8];
    }
    sPM[e*16+jq]=acc0; sPM[e*16+jq+8]=acc1;
  }
  __syncthreads();

  // Ph7: pos_m = v_ij * pm  -> atomic scatter into Pagg[rec]
  {
    const int e = t>>3, q = t&7;
    float* pg = Pagg + (size_t)sR[e]*128;
    #pragma unroll
    for(int i=0;i<4;i++){
      int f = q + i*8;                      // float4 index; channel o = f>>1
      float4 vv = *(const float4*)(Bv + e*ST + f*4);
      float pmv = sPM[e*16 + (f>>1)];
      atomicAdd(pg + f*4 + 0, vv.x*pmv);
      atomicAdd(pg + f*4 + 1, vv.y*pmv);
      atomicAdd(pg + f*4 + 2, vv.z*pmv);
      atomicAdd(pg + f*4 + 3, vv.w*pmv);
    }
  }
}

// ---------------- node kernel: scalar MLP + GP layer + MVLayerNorm ----------------
__global__ __launch_bounds__(256) void k_node(
    const float* __restrict__ s, const float* __restrict__ v,
    const float* __restrict__ uW1, const float* __restrict__ ub1,
    const float* __restrict__ uW2, const float* __restrict__ ub2,
    const float* __restrict__ glw, const float* __restrict__ glb,
    const float* __restrict__ grw, const float* __restrict__ grb,
    const float* __restrict__ gow, const float* __restrict__ gob,
    const float* __restrict__ lna,
    const float* __restrict__ Magg, const float* __restrict__ Pagg,
    const int* __restrict__ deg,
    float* __restrict__ outS, float* __restrict__ outV)
{
  __shared__ float sX[16*256];
  __shared__ float sT[16*128];
  __shared__ float sP[16*128];
  __shared__ float sG[16*128];
  __shared__ float sNrm[256];
  __shared__ float sInv[16];
  const int t = threadIdx.x;
  const int nb = blockIdx.x*16;
  if(t<16) sInv[t] = rsqrtf((float)deg[nb+t]);
  __syncthreads();
  for(int i=t;i<16*256;i+=256){
    int n=i>>8, c=i&255;
    sX[i] = (c<128) ? s[(size_t)(nb+n)*128 + c]
                    : Magg[(size_t)(nb+n)*128 + (c-128)]*sInv[n];
  }
  for(int i=t;i<16*128;i+=256){
    sP[i] = Pagg[(size_t)nb*128 + i]*sInv[i>>7];
  }
  __syncthreads();
  // u1: relu(x@uW1+b1)
  {
    const int j = t&127, ng = t>>7;
    float acc[8]; const float bb=ub1[j];
    #pragma unroll
    for(int n=0;n<8;n++) acc[n]=bb;
    for(int k=0;k<256;k++){
      float w = uW1[(size_t)k*128+j];
      #pragma unroll
      for(int n=0;n<8;n++) acc[n] += sX[(ng*8+n)*256 + k]*w;
    }
    #pragma unroll
    for(int n=0;n<8;n++) sT[(ng*8+n)*128 + j] = frelu(acc[n]);
  }
  __syncthreads();
  // u2 + residual -> s_new
  {
    const int j = t&127, ng = t>>7;
    float acc[8]; const float bb=ub2[j];
    #pragma unroll
    for(int n=0;n<8;n++) acc[n]=bb;
    for(int k=0;k<128;k++){
      float w = uW2[(size_t)k*128+j];
      #pragma unroll
      for(int n=0;n<8;n++) acc[n] += sT[(ng*8+n)*128 + k]*w;
    }
    #pragma unroll
    for(int n=0;n<8;n++){
      const size_t r = (size_t)(nb + ng*8 + n)*128 + j;
      outS[r] = s[r] + acc[n];
    }
  }
  // P4: vl, vr (mv_linear of p_aggr), then channelwise geometric product
  float vo[8];
  {
    const int n = t>>4, o = t&15;
    float vl[8], vr[8];
    #pragma unroll
    for(int b=0;b<8;b++){vl[b]=0.f; vr[b]=0.f;}
    vl[0]=glb[o]; vr[0]=grb[o];
    #pragma unroll
    for(int c=0;c<16;c++){
      float4 pa=*(const float4*)(sP + n*128 + c*8);
      float4 pb=*(const float4*)(sP + n*128 + c*8 + 4);
      float4 ga=*(const float4*)(glw + (o*16+c)*4);
      float4 gb=*(const float4*)(grw + (o*16+c)*4);
      vl[0]+=pa.x*ga.x; vl[1]+=pa.y*ga.y; vl[2]+=pa.z*ga.y; vl[3]+=pa.w*ga.y;
      vl[4]+=pb.x*ga.z; vl[5]+=pb.y*ga.z; vl[6]+=pb.z*ga.z; vl[7]+=pb.w*ga.w;
      vr[0]+=pa.x*gb.x; vr[1]+=pa.y*gb.y; vr[2]+=pa.z*gb.y; vr[3]+=pa.w*gb.y;
      vr[4]+=pb.x*gb.z; vr[5]+=pb.y*gb.z; vr[6]+=pb.z*gb.z; vr[7]+=pb.w*gb.w;
    }
    float g[8];
    #pragma unroll
    for(int b=0;b<8;b++) g[b]=0.f;
    const int MASKS[8]={0,1,2,4,3,5,6,7};   // blade masks; also the mask->index map
    #pragma unroll
    for(int i=0;i<8;i++){
      #pragma unroll
      for(int jj=0;jj<8;jj++){
        const int a=MASKS[i], b=MASKS[jj];
        const int kk=MASKS[a^b];
        int sg=1;
        for(int tt=a>>1; tt; tt>>=1) if(__popc(tt&b)&1) sg=-sg;
        const float pr = vl[i]*vr[jj];
        g[kk] += (sg>0)? pr : -pr;
      }
    }
    *(float4*)(sG + n*128 + o*8)     = make_float4(g[0],g[1],g[2],g[3]);
    *(float4*)(sG + n*128 + o*8 + 4) = make_float4(g[4],g[5],g[6],g[7]);
  }
  __syncthreads();
  // P5: vo = mv_linear(concat([gp, p_aggr], ch), go) ; per-channel norm
  {
    const int n = t>>4, o = t&15;
    #pragma unroll
    for(int b=0;b<8;b++) vo[b]=0.f;
    vo[0]=gob[o];
    #pragma unroll
    for(int c=0;c<32;c++){
      const float* src = (c<16) ? (sG + n*128 + c*8) : (sP + n*128 + (c-16)*8);
      float4 sa=*(const float4*)(src);
      float4 sb=*(const float4*)(src+4);
      float4 gw=*(const float4*)(gow + (o*32+c)*4);
      vo[0]+=sa.x*gw.x; vo[1]+=sa.y*gw.y; vo[2]+=sa.z*gw.y; vo[3]+=sa.w*gw.y;
      vo[4]+=sb.x*gw.z; vo[5]+=sb.y*gw.z; vo[6]+=sb.z*gw.z; vo[7]+=sb.w*gw.w;
    }
    float ssum=0.f;
    #pragma unroll
    for(int b=0;b<8;b++) ssum+=vo[b]*vo[b];
    sNrm[t]=sqrtf(ssum);
  }
  __syncthreads();
  // MVLayerNorm + residual -> v_new
  {
    const int n = t>>4, o = t&15;
    float mn=0.f;
    #pragma unroll
    for(int c=0;c<16;c++) mn += sNrm[n*16+c];
    mn = mn*(1.f/16.f) + 1e-6f;
    const float sc = lna[o]/mn;
    const size_t base = (size_t)(nb+n)*128 + o*8;
    float4 v0=*(const float4*)(v+base);
    float4 v1=*(const float4*)(v+base+4);
    *(float4*)(outV+base)   = make_float4(vo[0]*sc+v0.x, vo[1]*sc+v0.y, vo[2]*sc+v0.z, vo[3]*sc+v0.w);
    *(float4*)(outV+base+4) = make_float4(vo[4]*sc+v1.x, vo[5]*sc+v1.y, vo[6]*sc+v1.z, vo[7]*sc+v1.w);
  }
}

extern "C" void kernel_launch(void* const* d_in, const int* in_sizes, int n_in,
                              void* d_out, int out_size, void* d_ws, size_t ws_size,
                              hipStream_t stream){
  (void)in_sizes; (void)n_in; (void)out_size; (void)ws_size;
  const float* s    = (const float*)d_in[0];
  const float* v    = (const float*)d_in[1];
  const int*   eidx = (const int*)d_in[2];
  const float* Wvw  = (const float*)d_in[3];
  const float* Wvb  = (const float*)d_in[4];
  const float* mnW1 = (const float*)d_in[5];
  const float* mnb1 = (const float*)d_in[6];
  const float* mnW2 = (const float*)d_in[7];
  const float* mnb2 = (const float*)d_in[8];
  const float* pnW1 = (const float*)d_in[9];
  const float* pnb1 = (const float*)d_in[10];
  const float* pnW2 = (const float*)d_in[11];
  const float* pnb2 = (const float*)d_in[12];
  const float* unW1 = (const float*)d_in[13];
  const float* unb1 = (const float*)d_in[14];
  const float* unW2 = (const float*)d_in[15];
  const float* unb2 = (const float*)d_in[16];
  const float* glw  = (const float*)d_in[17];
  const float* glb  = (const float*)d_in[18];
  const float* grw  = (const float*)d_in[19];
  const float* grb  = (const float*)d_in[20];
  const float* gow  = (const float*)d_in[21];
  const float* gob  = (const float*)d_in[22];
  const float* lna  = (const float*)d_in[23];

  float* outS = (float*)d_out;
  float* outV = outS + (size_t)NN*128;
  // A/B scratch lives in d_out (dead before k_node overwrites it)
  float* A    = outS;
  float* Bn   = outV;
  float* ws   = (float*)d_ws;
  float* Magg = ws;
  float* Pagg = ws + (size_t)NN*128;
  int*   deg  = (int*)(ws + (size_t)2*NN*128);

  hipMemsetAsync(Magg, 0, (size_t)2*NN*128*sizeof(float) + (size_t)NN*sizeof(int), stream);
  k_deg<<<NE/256, 256, 0, stream>>>(eidx, deg);
  k_ab<<<NN/8, 256, 0, stream>>>(s, mnW1, A, Bn);
  k_edge<<<NE/ET, 256, 0, stream>>>(v, eidx, Wvw, Wvb, mnW1 + 256*128, mnb1,
                                    mnW2, mnb2, pnW1, pnb1, pnW2, pnb2,
                                    A, Bn, Magg, Pagg);
  k_node<<<NN/16, 256, 0, stream>>>(s, v, unW1, unb1, unW2, unb2,
                                    glw, glb, grw, grb, gow, gob, lna,
                                    Magg, Pagg, deg, outS, outV);
}